// Round 2
// baseline (200.346 us; speedup 1.0000x reference)
//
#include <hip/hip_runtime.h>
#include <hip/hip_bf16.h>

// GAT, 2 layers, N=8192 nodes, sparse adjacency (~270K edges incl. self-loops).
// Masked softmax with -1e9 fill == sparse neighbor softmax (exp underflows to 0).
// All fp32. Workspace layout (needs ~25.5 MB):
//   [0,8MB)    h1[8192][256]
//   [8,16MB)   out1[8192][256]  (post-ELU layer-1 output)
//   [16,24MB)  bitmap[8192][256] uint32 adjacency bits
//   [24MB..)   f1s[8192], f1d[8192], h2[8192][16], f2s[8192], f2d[8192]

#define NN 8192

// ---------- GEMM1: h1 = x(8192x512) @ W1(512x256), fp32 ----------
__global__ __launch_bounds__(256) void gemm1_kernel(const float* __restrict__ A,
                                                    const float* __restrict__ B,
                                                    float* __restrict__ C) {
  constexpr int K = 512, N = 256;
  __shared__ float As[16][68];  // As[k][m], stride 68 floats (16B-aligned rows)
  __shared__ float Bs[16][68];  // Bs[k][n]
  const int tid = threadIdx.x;
  const int bm = blockIdx.x * 64;
  const int bn = blockIdx.y * 64;
  const int tx = tid & 15, ty = tid >> 4;
  const int arow = tid >> 2, acol = (tid & 3) << 2;   // A: 64 rows x 16 k, float4 along k
  const int brow = tid >> 4, bcol = (tid & 15) << 2;  // B: 16 k x 64 n, float4 along n
  float acc[4][4] = {};
  for (int k0 = 0; k0 < K; k0 += 16) {
    const float4 av = *(const float4*)(A + (size_t)(bm + arow) * K + (k0 + acol));
    const float4 bv = *(const float4*)(B + (size_t)(k0 + brow) * N + (bn + bcol));
    __syncthreads();
    As[acol + 0][arow] = av.x;
    As[acol + 1][arow] = av.y;
    As[acol + 2][arow] = av.z;
    As[acol + 3][arow] = av.w;
    *(float4*)&Bs[brow][bcol] = bv;
    __syncthreads();
#pragma unroll
    for (int kk = 0; kk < 16; ++kk) {
      const float4 a4 = *(const float4*)&As[kk][ty << 2];
      const float4 b4 = *(const float4*)&Bs[kk][tx << 2];
      const float ar[4] = {a4.x, a4.y, a4.z, a4.w};
      const float br[4] = {b4.x, b4.y, b4.z, b4.w};
#pragma unroll
      for (int i = 0; i < 4; ++i)
#pragma unroll
        for (int j = 0; j < 4; ++j) acc[i][j] = fmaf(ar[i], br[j], acc[i][j]);
    }
  }
#pragma unroll
  for (int i = 0; i < 4; ++i) {
    float4 v = {acc[i][0], acc[i][1], acc[i][2], acc[i][3]};
    *(float4*)(C + (size_t)(bm + (ty << 2) + i) * N + bn + (tx << 2)) = v;
  }
}

// ---------- f1: per-row dots of h1 with a1_src / a1_dst ----------
__global__ __launch_bounds__(256) void f1_kernel(const float* __restrict__ h1,
                                                 const float* __restrict__ a_src,
                                                 const float* __restrict__ a_dst,
                                                 float* __restrict__ fs,
                                                 float* __restrict__ fd) {
  const int lane = threadIdx.x & 63;
  const int row = blockIdx.x * 4 + (threadIdx.x >> 6);
  const float4 hv = *(const float4*)(h1 + (size_t)row * 256 + lane * 4);
  const float4 as = *(const float4*)(a_src + lane * 4);
  const float4 ad = *(const float4*)(a_dst + lane * 4);
  float ss = hv.x * as.x + hv.y * as.y + hv.z * as.z + hv.w * as.w;
  float dd = hv.x * ad.x + hv.y * ad.y + hv.z * ad.z + hv.w * ad.w;
#pragma unroll
  for (int off = 32; off; off >>= 1) {
    ss += __shfl_xor(ss, off);
    dd += __shfl_xor(dd, off);
  }
  if (lane == 0) {
    fs[row] = ss;
    fd[row] = dd;
  }
}

// ---------- scatter edges into bitmap ----------
__global__ void scatter_kernel(const int* __restrict__ ei, int E,
                               unsigned* __restrict__ bitmap) {
  const int t = blockIdx.x * 256 + threadIdx.x;
  if (t >= E) return;
  const int s = ei[t];
  const int d = ei[E + t];
  atomicOr(bitmap + (size_t)s * 256 + (d >> 5), 1u << (d & 31));
}

// ---------- layer-1 attention: online softmax over neighbors, out=elu(attn@h1) ----------
__global__ __launch_bounds__(256) void attn1_kernel(const unsigned* __restrict__ bitmap,
                                                    const float* __restrict__ h1,
                                                    const float* __restrict__ fs,
                                                    const float* __restrict__ fd,
                                                    float* __restrict__ out1) {
  const int lane = threadIdx.x & 63;
  const int row = blockIdx.x * 4 + (threadIdx.x >> 6);
  const unsigned* brow = bitmap + (size_t)row * 256;
  const float fsr = fs[row];
  float4 acc = {0.f, 0.f, 0.f, 0.f};
  float m = -1e30f, s = 0.f;
  for (int w = 0; w < 256; ++w) {
    unsigned word = brow[w];
    while (word) {
      const int b = __ffs(word) - 1;
      word &= word - 1;
      const int j = w * 32 + b;
      float e = fsr + fd[j];
      e = e > 0.f ? e : 0.2f * e;  // leaky_relu(0.2)
      const float4 hv = *(const float4*)(h1 + (size_t)j * 256 + lane * 4);
      if (e > m) {  // wave-uniform branch
        const float scale = expf(m - e);  // first iter: exp(-inf) = 0
        const float wgt = 1.f;            // exp(e - e)
        acc.x = acc.x * scale + wgt * hv.x;
        acc.y = acc.y * scale + wgt * hv.y;
        acc.z = acc.z * scale + wgt * hv.z;
        acc.w = acc.w * scale + wgt * hv.w;
        s = s * scale + wgt;
        m = e;
      } else {
        const float wgt = expf(e - m);
        acc.x += wgt * hv.x;
        acc.y += wgt * hv.y;
        acc.z += wgt * hv.z;
        acc.w += wgt * hv.w;
        s += wgt;
      }
    }
  }
  const float inv = 1.f / s;
  float4 v = {acc.x * inv, acc.y * inv, acc.z * inv, acc.w * inv};
  v.x = v.x > 0.f ? v.x : expf(v.x) - 1.f;  // elu
  v.y = v.y > 0.f ? v.y : expf(v.y) - 1.f;
  v.z = v.z > 0.f ? v.z : expf(v.z) - 1.f;
  v.w = v.w > 0.f ? v.w : expf(v.w) - 1.f;
  *(float4*)(out1 + (size_t)row * 256 + lane * 4) = v;
}

// ---------- GEMM2: h2 = out1(8192x256) @ W2(256x16) ----------
__global__ __launch_bounds__(256) void gemm2_kernel(const float* __restrict__ out1,
                                                    const float* __restrict__ W2,
                                                    float* __restrict__ h2) {
  __shared__ float Ws[256 * 16];
  for (int i = threadIdx.x; i < 256 * 16; i += 256) Ws[i] = W2[i];
  __syncthreads();
  const int r = threadIdx.x >> 4, c = threadIdx.x & 15;
  const int row = blockIdx.x * 16 + r;
  const float* arow = out1 + (size_t)row * 256;
  float acc = 0.f;
#pragma unroll 8
  for (int k = 0; k < 256; ++k) acc = fmaf(arow[k], Ws[k * 16 + c], acc);
  h2[(size_t)row * 16 + c] = acc;
}

// ---------- f2: per-row dots of h2 with a2_src / a2_dst ----------
__global__ void f2_kernel(const float* __restrict__ h2, const float* __restrict__ a_src,
                          const float* __restrict__ a_dst, float* __restrict__ fs,
                          float* __restrict__ fd) {
  const int row = blockIdx.x * blockDim.x + threadIdx.x;
  if (row >= NN) return;
  float s = 0.f, d = 0.f;
#pragma unroll
  for (int k = 0; k < 16; ++k) {
    const float h = h2[(size_t)row * 16 + k];
    s = fmaf(h, a_src[k], s);
    d = fmaf(h, a_dst[k], d);
  }
  fs[row] = s;
  fd[row] = d;
}

// ---------- layer-2 attention + final log_softmax over 16 classes ----------
__global__ __launch_bounds__(256) void attn2_kernel(const unsigned* __restrict__ bitmap,
                                                    const float* __restrict__ h2,
                                                    const float* __restrict__ fs,
                                                    const float* __restrict__ fd,
                                                    float* __restrict__ out) {
  const int lane = threadIdx.x & 63;
  const int row = blockIdx.x * 4 + (threadIdx.x >> 6);
  const unsigned* brow = bitmap + (size_t)row * 256;
  const float fsr = fs[row];
  float acc = 0.f;
  float m = -1e30f, s = 0.f;
  for (int w = 0; w < 256; ++w) {
    unsigned word = brow[w];
    while (word) {
      const int b = __ffs(word) - 1;
      word &= word - 1;
      const int j = w * 32 + b;
      float e = fsr + fd[j];
      e = e > 0.f ? e : 0.2f * e;
      const float hv = (lane < 16) ? h2[(size_t)j * 16 + lane] : 0.f;
      if (e > m) {
        const float scale = expf(m - e);
        acc = acc * scale + hv;
        s = s * scale + 1.f;
        m = e;
      } else {
        const float wgt = expf(e - m);
        acc = fmaf(wgt, hv, acc);
        s += wgt;
      }
    }
  }
  const float v = acc / s;  // logits, valid in lanes 0..15
  // log_softmax across the 16 classes (16-wide shuffles)
  float mx = v;
#pragma unroll
  for (int off = 8; off; off >>= 1) mx = fmaxf(mx, __shfl_xor(mx, off, 16));
  float se = expf(v - mx);
#pragma unroll
  for (int off = 8; off; off >>= 1) se += __shfl_xor(se, off, 16);
  if (lane < 16) out[(size_t)row * 16 + lane] = v - mx - logf(se);
}

extern "C" void kernel_launch(void* const* d_in, const int* in_sizes, int n_in,
                              void* d_out, int out_size, void* d_ws, size_t ws_size,
                              hipStream_t stream) {
  const float* x = (const float*)d_in[0];
  const int* ei = (const int*)d_in[1];
  const float* W1 = (const float*)d_in[2];
  const float* a1s = (const float*)d_in[3];
  const float* a1d = (const float*)d_in[4];
  const float* W2 = (const float*)d_in[5];
  const float* a2s = (const float*)d_in[6];
  const float* a2d = (const float*)d_in[7];
  float* out = (float*)d_out;
  const int E = in_sizes[1] / 2;

  char* ws = (char*)d_ws;
  float* h1 = (float*)ws;                              // 8 MB
  float* out1 = (float*)(ws + (8u << 20));             // 8 MB
  unsigned* bitmap = (unsigned*)(ws + (16u << 20));    // 8 MB
  float* f1s = (float*)(ws + (24u << 20));
  float* f1d = f1s + NN;
  float* h2 = f1d + NN;                                // 512 KB
  float* f2s = h2 + (size_t)NN * 16;
  float* f2d = f2s + NN;

  hipMemsetAsync(bitmap, 0, (size_t)NN * 256 * sizeof(unsigned), stream);
  scatter_kernel<<<(E + 255) / 256, 256, 0, stream>>>(ei, E, bitmap);
  gemm1_kernel<<<dim3(NN / 64, 256 / 64), 256, 0, stream>>>(x, W1, h1);
  f1_kernel<<<NN / 4, 256, 0, stream>>>(h1, a1s, a1d, f1s, f1d);
  attn1_kernel<<<NN / 4, 256, 0, stream>>>(bitmap, h1, f1s, f1d, out1);
  gemm2_kernel<<<NN / 16, 256, 0, stream>>>(out1, W2, h2);
  f2_kernel<<<NN / 256, 256, 0, stream>>>(h2, a2s, a2d, f2s, f2d);
  attn2_kernel<<<NN / 4, 256, 0, stream>>>(bitmap, h2, f2s, f2d, out);
}

// Round 3
// 199.802 us; speedup vs baseline: 1.0027x; 1.0027x over previous
//
#include <hip/hip_runtime.h>
#include <hip/hip_bf16.h>

// GAT, 2 layers, N=8192 nodes, sparse adjacency (~270K edges incl. self-loops).
// Masked softmax with -1e9 fill == sparse neighbor softmax (exp underflows to 0).
// All fp32. Workspace layout (needs ~25.5 MB):
//   [0,8MB)    h1[8192][256]
//   [8,16MB)   out1[8192][256]  (post-ELU layer-1 output)
//   [16,24MB)  bitmap[8192][256] uint32 adjacency bits
//   [24MB..)   f1s[8192], f1d[8192], h2[8192][16], f2s[8192], f2d[8192]

#define NN 8192

// ---------- GEMM1: h1 = x(8192x512) @ W1(512x256), fp32 ----------
__global__ __launch_bounds__(256) void gemm1_kernel(const float* __restrict__ A,
                                                    const float* __restrict__ B,
                                                    float* __restrict__ C) {
  constexpr int K = 512, N = 256;
  __shared__ float As[16][68];  // As[k][m], stride 68 floats (16B-aligned rows)
  __shared__ float Bs[16][68];  // Bs[k][n]
  const int tid = threadIdx.x;
  const int bm = blockIdx.x * 64;
  const int bn = blockIdx.y * 64;
  const int tx = tid & 15, ty = tid >> 4;
  const int arow = tid >> 2, acol = (tid & 3) << 2;   // A: 64 rows x 16 k, float4 along k
  const int brow = tid >> 4, bcol = (tid & 15) << 2;  // B: 16 k x 64 n, float4 along n
  float acc[4][4] = {};
  for (int k0 = 0; k0 < K; k0 += 16) {
    const float4 av = *(const float4*)(A + (size_t)(bm + arow) * K + (k0 + acol));
    const float4 bv = *(const float4*)(B + (size_t)(k0 + brow) * N + (bn + bcol));
    __syncthreads();
    As[acol + 0][arow] = av.x;
    As[acol + 1][arow] = av.y;
    As[acol + 2][arow] = av.z;
    As[acol + 3][arow] = av.w;
    *(float4*)&Bs[brow][bcol] = bv;
    __syncthreads();
#pragma unroll
    for (int kk = 0; kk < 16; ++kk) {
      const float4 a4 = *(const float4*)&As[kk][ty << 2];
      const float4 b4 = *(const float4*)&Bs[kk][tx << 2];
      const float ar[4] = {a4.x, a4.y, a4.z, a4.w};
      const float br[4] = {b4.x, b4.y, b4.z, b4.w};
#pragma unroll
      for (int i = 0; i < 4; ++i)
#pragma unroll
        for (int j = 0; j < 4; ++j) acc[i][j] = fmaf(ar[i], br[j], acc[i][j]);
    }
  }
#pragma unroll
  for (int i = 0; i < 4; ++i) {
    float4 v = {acc[i][0], acc[i][1], acc[i][2], acc[i][3]};
    *(float4*)(C + (size_t)(bm + (ty << 2) + i) * N + bn + (tx << 2)) = v;
  }
}

// ---------- f1: per-row dots of h1 with a1_src / a1_dst ----------
__global__ __launch_bounds__(256) void f1_kernel(const float* __restrict__ h1,
                                                 const float* __restrict__ a_src,
                                                 const float* __restrict__ a_dst,
                                                 float* __restrict__ fs,
                                                 float* __restrict__ fd) {
  const int lane = threadIdx.x & 63;
  const int row = blockIdx.x * 4 + (threadIdx.x >> 6);
  const float4 hv = *(const float4*)(h1 + (size_t)row * 256 + lane * 4);
  const float4 as = *(const float4*)(a_src + lane * 4);
  const float4 ad = *(const float4*)(a_dst + lane * 4);
  float ss = hv.x * as.x + hv.y * as.y + hv.z * as.z + hv.w * as.w;
  float dd = hv.x * ad.x + hv.y * ad.y + hv.z * ad.z + hv.w * ad.w;
#pragma unroll
  for (int off = 32; off; off >>= 1) {
    ss += __shfl_xor(ss, off);
    dd += __shfl_xor(dd, off);
  }
  if (lane == 0) {
    fs[row] = ss;
    fd[row] = dd;
  }
}

// ---------- scatter edges into bitmap ----------
__global__ void scatter_kernel(const int* __restrict__ ei, int E,
                               unsigned* __restrict__ bitmap) {
  const int t = blockIdx.x * 256 + threadIdx.x;
  if (t >= E) return;
  const int s = ei[t];
  const int d = ei[E + t];
  atomicOr(bitmap + (size_t)s * 256 + (d >> 5), 1u << (d & 31));
}

// ---------- layer-1 attention: online softmax over neighbors, out=elu(attn@h1) ----------
__global__ __launch_bounds__(256) void attn1_kernel(const unsigned* __restrict__ bitmap,
                                                    const float* __restrict__ h1,
                                                    const float* __restrict__ fs,
                                                    const float* __restrict__ fd,
                                                    float* __restrict__ out1) {
  const int lane = threadIdx.x & 63;
  const int row = blockIdx.x * 4 + (threadIdx.x >> 6);
  const unsigned* brow = bitmap + (size_t)row * 256;
  const float fsr = fs[row];
  float4 acc = {0.f, 0.f, 0.f, 0.f};
  float m = -1e30f, s = 0.f;
  for (int w = 0; w < 256; ++w) {
    unsigned word = brow[w];
    while (word) {
      const int b = __ffs(word) - 1;
      word &= word - 1;
      const int j = w * 32 + b;
      float e = fsr + fd[j];
      e = e > 0.f ? e : 0.2f * e;  // leaky_relu(0.2)
      const float4 hv = *(const float4*)(h1 + (size_t)j * 256 + lane * 4);
      if (e > m) {  // wave-uniform branch
        const float scale = expf(m - e);  // first iter: exp(-inf) = 0
        const float wgt = 1.f;            // exp(e - e)
        acc.x = acc.x * scale + wgt * hv.x;
        acc.y = acc.y * scale + wgt * hv.y;
        acc.z = acc.z * scale + wgt * hv.z;
        acc.w = acc.w * scale + wgt * hv.w;
        s = s * scale + wgt;
        m = e;
      } else {
        const float wgt = expf(e - m);
        acc.x += wgt * hv.x;
        acc.y += wgt * hv.y;
        acc.z += wgt * hv.z;
        acc.w += wgt * hv.w;
        s += wgt;
      }
    }
  }
  const float inv = 1.f / s;
  float4 v = {acc.x * inv, acc.y * inv, acc.z * inv, acc.w * inv};
  v.x = v.x > 0.f ? v.x : expf(v.x) - 1.f;  // elu
  v.y = v.y > 0.f ? v.y : expf(v.y) - 1.f;
  v.z = v.z > 0.f ? v.z : expf(v.z) - 1.f;
  v.w = v.w > 0.f ? v.w : expf(v.w) - 1.f;
  *(float4*)(out1 + (size_t)row * 256 + lane * 4) = v;
}

// ---------- GEMM2: h2 = out1(8192x256) @ W2(256x16) ----------
__global__ __launch_bounds__(256) void gemm2_kernel(const float* __restrict__ out1,
                                                    const float* __restrict__ W2,
                                                    float* __restrict__ h2) {
  __shared__ float Ws[256 * 16];
  for (int i = threadIdx.x; i < 256 * 16; i += 256) Ws[i] = W2[i];
  __syncthreads();
  const int r = threadIdx.x >> 4, c = threadIdx.x & 15;
  const int row = blockIdx.x * 16 + r;
  const float* arow = out1 + (size_t)row * 256;
  float acc = 0.f;
#pragma unroll 8
  for (int k = 0; k < 256; ++k) acc = fmaf(arow[k], Ws[k * 16 + c], acc);
  h2[(size_t)row * 16 + c] = acc;
}

// ---------- f2: per-row dots of h2 with a2_src / a2_dst ----------
__global__ void f2_kernel(const float* __restrict__ h2, const float* __restrict__ a_src,
                          const float* __restrict__ a_dst, float* __restrict__ fs,
                          float* __restrict__ fd) {
  const int row = blockIdx.x * blockDim.x + threadIdx.x;
  if (row >= NN) return;
  float s = 0.f, d = 0.f;
#pragma unroll
  for (int k = 0; k < 16; ++k) {
    const float h = h2[(size_t)row * 16 + k];
    s = fmaf(h, a_src[k], s);
    d = fmaf(h, a_dst[k], d);
  }
  fs[row] = s;
  fd[row] = d;
}

// ---------- layer-2 attention + final log_softmax over 16 classes ----------
__global__ __launch_bounds__(256) void attn2_kernel(const unsigned* __restrict__ bitmap,
                                                    const float* __restrict__ h2,
                                                    const float* __restrict__ fs,
                                                    const float* __restrict__ fd,
                                                    float* __restrict__ out) {
  const int lane = threadIdx.x & 63;
  const int row = blockIdx.x * 4 + (threadIdx.x >> 6);
  const unsigned* brow = bitmap + (size_t)row * 256;
  const float fsr = fs[row];
  float acc = 0.f;
  float m = -1e30f, s = 0.f;
  for (int w = 0; w < 256; ++w) {
    unsigned word = brow[w];
    while (word) {
      const int b = __ffs(word) - 1;
      word &= word - 1;
      const int j = w * 32 + b;
      float e = fsr + fd[j];
      e = e > 0.f ? e : 0.2f * e;
      const float hv = (lane < 16) ? h2[(size_t)j * 16 + lane] : 0.f;
      if (e > m) {
        const float scale = expf(m - e);
        acc = acc * scale + hv;
        s = s * scale + 1.f;
        m = e;
      } else {
        const float wgt = expf(e - m);
        acc = fmaf(wgt, hv, acc);
        s += wgt;
      }
    }
  }
  const float v = acc / s;  // logits, valid in lanes 0..15
  // log_softmax across the 16 classes (16-wide shuffles)
  float mx = v;
#pragma unroll
  for (int off = 8; off; off >>= 1) mx = fmaxf(mx, __shfl_xor(mx, off, 16));
  float se = expf(v - mx);
#pragma unroll
  for (int off = 8; off; off >>= 1) se += __shfl_xor(se, off, 16);
  if (lane < 16) out[(size_t)row * 16 + lane] = v - mx - logf(se);
}

extern "C" void kernel_launch(void* const* d_in, const int* in_sizes, int n_in,
                              void* d_out, int out_size, void* d_ws, size_t ws_size,
                              hipStream_t stream) {
  const float* x = (const float*)d_in[0];
  const int* ei = (const int*)d_in[1];
  const float* W1 = (const float*)d_in[2];
  const float* a1s = (const float*)d_in[3];
  const float* a1d = (const float*)d_in[4];
  const float* W2 = (const float*)d_in[5];
  const float* a2s = (const float*)d_in[6];
  const float* a2d = (const float*)d_in[7];
  float* out = (float*)d_out;
  const int E = in_sizes[1] / 2;

  char* ws = (char*)d_ws;
  float* h1 = (float*)ws;                              // 8 MB
  float* out1 = (float*)(ws + (8u << 20));             // 8 MB
  unsigned* bitmap = (unsigned*)(ws + (16u << 20));    // 8 MB
  float* f1s = (float*)(ws + (24u << 20));
  float* f1d = f1s + NN;
  float* h2 = f1d + NN;                                // 512 KB
  float* f2s = h2 + (size_t)NN * 16;
  float* f2d = f2s + NN;

  hipMemsetAsync(bitmap, 0, (size_t)NN * 256 * sizeof(unsigned), stream);
  scatter_kernel<<<(E + 255) / 256, 256, 0, stream>>>(ei, E, bitmap);
  gemm1_kernel<<<dim3(NN / 64, 256 / 64), 256, 0, stream>>>(x, W1, h1);
  f1_kernel<<<NN / 4, 256, 0, stream>>>(h1, a1s, a1d, f1s, f1d);
  attn1_kernel<<<NN / 4, 256, 0, stream>>>(bitmap, h1, f1s, f1d, out1);
  gemm2_kernel<<<NN / 16, 256, 0, stream>>>(out1, W2, h2);
  f2_kernel<<<NN / 256, 256, 0, stream>>>(h2, a2s, a2d, f2s, f2d);
  attn2_kernel<<<NN / 4, 256, 0, stream>>>(bitmap, h2, f2s, f2d, out);
}

// Round 4
// 103.632 us; speedup vs baseline: 1.9332x; 1.9280x over previous
//
#include <hip/hip_runtime.h>
#include <hip/hip_bf16.h>

// GAT, 2 layers, N=8192 nodes, sparse adjacency (~270K edges incl. self-loops).
// Masked softmax with -1e9 fill == sparse neighbor softmax (exp underflows to 0).
// All fp32. Round 3: CSR-ified attention.
//   - build_csr compacts the dedup bitmap into ushort neighbor lists IN PLACE
//     (bitmap row = 1KB holds up to 512 ushort indices; bitmap dead afterward).
//   - attention kernels: parallel weight computation across lanes (no serial
//     exp chain, no online-softmax rescale) + x4-unrolled gather for MLP.
// Workspace layout (~24.8 MB):
//   [0,8MB)    h1[8192][256]
//   [8,16MB)   out1[8192][256]  (post-ELU layer-1 output)
//   [16,24MB)  bitmap[8192][256] uint32  -> reused as nbr ushort[8192][512]
//   [24MB..)   f1s[8192], f1d[8192], h2[8192][16], f2s[8192], f2d[8192], deg[8192]

#define NN 8192
#define MAXD 128  // slots handled in weight phase; P(in-degree>128) ~ 1e-18

// ---------- GEMM1: h1 = x(8192x512) @ W1(512x256), fp32 ----------
__global__ __launch_bounds__(256) void gemm1_kernel(const float* __restrict__ A,
                                                    const float* __restrict__ B,
                                                    float* __restrict__ C) {
  constexpr int K = 512, N = 256;
  __shared__ float As[16][68];
  __shared__ float Bs[16][68];
  const int tid = threadIdx.x;
  const int bm = blockIdx.x * 64;
  const int bn = blockIdx.y * 64;
  const int tx = tid & 15, ty = tid >> 4;
  const int arow = tid >> 2, acol = (tid & 3) << 2;
  const int brow = tid >> 4, bcol = (tid & 15) << 2;
  float acc[4][4] = {};
  for (int k0 = 0; k0 < K; k0 += 16) {
    const float4 av = *(const float4*)(A + (size_t)(bm + arow) * K + (k0 + acol));
    const float4 bv = *(const float4*)(B + (size_t)(k0 + brow) * N + (bn + bcol));
    __syncthreads();
    As[acol + 0][arow] = av.x;
    As[acol + 1][arow] = av.y;
    As[acol + 2][arow] = av.z;
    As[acol + 3][arow] = av.w;
    *(float4*)&Bs[brow][bcol] = bv;
    __syncthreads();
#pragma unroll
    for (int kk = 0; kk < 16; ++kk) {
      const float4 a4 = *(const float4*)&As[kk][ty << 2];
      const float4 b4 = *(const float4*)&Bs[kk][tx << 2];
      const float ar[4] = {a4.x, a4.y, a4.z, a4.w};
      const float br[4] = {b4.x, b4.y, b4.z, b4.w};
#pragma unroll
      for (int i = 0; i < 4; ++i)
#pragma unroll
        for (int j = 0; j < 4; ++j) acc[i][j] = fmaf(ar[i], br[j], acc[i][j]);
    }
  }
#pragma unroll
  for (int i = 0; i < 4; ++i) {
    float4 v = {acc[i][0], acc[i][1], acc[i][2], acc[i][3]};
    *(float4*)(C + (size_t)(bm + (ty << 2) + i) * N + bn + (tx << 2)) = v;
  }
}

// ---------- f1: per-row dots of h1 with a1_src / a1_dst ----------
__global__ __launch_bounds__(256) void f1_kernel(const float* __restrict__ h1,
                                                 const float* __restrict__ a_src,
                                                 const float* __restrict__ a_dst,
                                                 float* __restrict__ fs,
                                                 float* __restrict__ fd) {
  const int lane = threadIdx.x & 63;
  const int row = blockIdx.x * 4 + (threadIdx.x >> 6);
  const float4 hv = *(const float4*)(h1 + (size_t)row * 256 + lane * 4);
  const float4 as = *(const float4*)(a_src + lane * 4);
  const float4 ad = *(const float4*)(a_dst + lane * 4);
  float ss = hv.x * as.x + hv.y * as.y + hv.z * as.z + hv.w * as.w;
  float dd = hv.x * ad.x + hv.y * ad.y + hv.z * ad.z + hv.w * ad.w;
#pragma unroll
  for (int off = 32; off; off >>= 1) {
    ss += __shfl_xor(ss, off);
    dd += __shfl_xor(dd, off);
  }
  if (lane == 0) {
    fs[row] = ss;
    fd[row] = dd;
  }
}

// ---------- scatter edges into bitmap (dedup via OR) ----------
__global__ void scatter_kernel(const int* __restrict__ ei, int E,
                               unsigned* __restrict__ bitmap) {
  const int t = blockIdx.x * 256 + threadIdx.x;
  if (t >= E) return;
  const int s = ei[t];
  const int d = ei[E + t];
  atomicOr(bitmap + (size_t)s * 256 + (d >> 5), 1u << (d & 31));
}

// ---------- build CSR in place over the bitmap ----------
// One wave per row. Each lane loads 4 consecutive words (uint4, one vector
// load instruction -> all reads complete before any store issues), popcount +
// shuffle prefix-scan gives each lane its write offset, then ushort neighbor
// indices are written into the row's own 1KB (dead bitmap storage).
__global__ __launch_bounds__(256) void build_csr_kernel(unsigned* __restrict__ bitmap,
                                                        int* __restrict__ deg) {
  const int lane = threadIdx.x & 63;
  const int row = blockIdx.x * 4 + (threadIdx.x >> 6);
  unsigned* brow = bitmap + (size_t)row * 256;
  const uint4 wv = *(const uint4*)(brow + lane * 4);
  const int cnt = __popc(wv.x) + __popc(wv.y) + __popc(wv.z) + __popc(wv.w);
  int inc = cnt;
#pragma unroll
  for (int d = 1; d < 64; d <<= 1) {
    const int t = __shfl_up(inc, d);
    if (lane >= d) inc += t;
  }
  int off = inc - cnt;  // exclusive prefix
  const int total = __shfl(inc, 63);
  unsigned short* nb = (unsigned short*)brow;
  const unsigned words[4] = {wv.x, wv.y, wv.z, wv.w};
  const int base_j = lane * 128;
#pragma unroll
  for (int q = 0; q < 4; ++q) {
    unsigned word = words[q];
    while (word) {
      const int b = __ffs(word) - 1;
      word &= word - 1;
      nb[off++] = (unsigned short)(base_j + q * 32 + b);
    }
  }
  if (lane == 0) deg[row] = total;
}

__device__ __forceinline__ float lrelu02(float e) { return e > 0.f ? e : 0.2f * e; }

// ---------- layer-1 attention: parallel weights + x4-unrolled gather ----------
__global__ __launch_bounds__(256) void attn1_kernel(const unsigned* __restrict__ bitmap,
                                                    const int* __restrict__ degarr,
                                                    const float* __restrict__ h1,
                                                    const float* __restrict__ fs,
                                                    const float* __restrict__ fd,
                                                    float* __restrict__ out1) {
  __shared__ float wsh[4][MAXD];
  __shared__ int jsh[4][MAXD];
  const int lane = threadIdx.x & 63;
  const int wv = threadIdx.x >> 6;
  const int row = blockIdx.x * 4 + wv;
  const unsigned short* nb = (const unsigned short*)(bitmap + (size_t)row * 256);
  const int deg = degarr[row];
  const float fsr = fs[row];
  // ---- weight phase: lane k handles neighbors k and k+64 in parallel ----
  const int j0 = (lane < deg) ? (int)nb[lane] : 0;
  const int j1 = (lane + 64 < deg) ? (int)nb[lane + 64] : 0;
  const float e0 = (lane < deg) ? lrelu02(fsr + fd[j0]) : -1e30f;
  const float e1 = (lane + 64 < deg) ? lrelu02(fsr + fd[j1]) : -1e30f;
  float m = fmaxf(e0, e1);
#pragma unroll
  for (int off = 32; off; off >>= 1) m = fmaxf(m, __shfl_xor(m, off));
  const float w0 = (lane < deg) ? expf(e0 - m) : 0.f;
  const float w1 = (lane + 64 < deg) ? expf(e1 - m) : 0.f;
  float s = w0 + w1;
#pragma unroll
  for (int off = 32; off; off >>= 1) s += __shfl_xor(s, off);
  wsh[wv][lane] = w0;
  jsh[wv][lane] = j0;
  wsh[wv][lane + 64] = w1;
  jsh[wv][lane + 64] = j1;
  // same-wave LDS produce->consume; compiler inserts lgkmcnt, no barrier needed
  // ---- gather phase: 4 independent loads in flight ----
  float4 acc = {0.f, 0.f, 0.f, 0.f};
  int t = 0;
  for (; t + 4 <= deg; t += 4) {
    const float W0 = wsh[wv][t], W1 = wsh[wv][t + 1], W2 = wsh[wv][t + 2], W3 = wsh[wv][t + 3];
    const int J0 = jsh[wv][t], J1 = jsh[wv][t + 1], J2 = jsh[wv][t + 2], J3 = jsh[wv][t + 3];
    const float4 v0 = *(const float4*)(h1 + (size_t)J0 * 256 + lane * 4);
    const float4 v1 = *(const float4*)(h1 + (size_t)J1 * 256 + lane * 4);
    const float4 v2 = *(const float4*)(h1 + (size_t)J2 * 256 + lane * 4);
    const float4 v3 = *(const float4*)(h1 + (size_t)J3 * 256 + lane * 4);
    acc.x = fmaf(W0, v0.x, fmaf(W1, v1.x, fmaf(W2, v2.x, fmaf(W3, v3.x, acc.x))));
    acc.y = fmaf(W0, v0.y, fmaf(W1, v1.y, fmaf(W2, v2.y, fmaf(W3, v3.y, acc.y))));
    acc.z = fmaf(W0, v0.z, fmaf(W1, v1.z, fmaf(W2, v2.z, fmaf(W3, v3.z, acc.z))));
    acc.w = fmaf(W0, v0.w, fmaf(W1, v1.w, fmaf(W2, v2.w, fmaf(W3, v3.w, acc.w))));
  }
  for (; t < deg; ++t) {
    const float W0 = wsh[wv][t];
    const int J0 = jsh[wv][t];
    const float4 v0 = *(const float4*)(h1 + (size_t)J0 * 256 + lane * 4);
    acc.x = fmaf(W0, v0.x, acc.x);
    acc.y = fmaf(W0, v0.y, acc.y);
    acc.z = fmaf(W0, v0.z, acc.z);
    acc.w = fmaf(W0, v0.w, acc.w);
  }
  const float inv = 1.f / s;
  float4 v = {acc.x * inv, acc.y * inv, acc.z * inv, acc.w * inv};
  v.x = v.x > 0.f ? v.x : expf(v.x) - 1.f;  // elu
  v.y = v.y > 0.f ? v.y : expf(v.y) - 1.f;
  v.z = v.z > 0.f ? v.z : expf(v.z) - 1.f;
  v.w = v.w > 0.f ? v.w : expf(v.w) - 1.f;
  *(float4*)(out1 + (size_t)row * 256 + lane * 4) = v;
}

// ---------- GEMM2: h2 = out1(8192x256) @ W2(256x16) ----------
__global__ __launch_bounds__(256) void gemm2_kernel(const float* __restrict__ out1,
                                                    const float* __restrict__ W2,
                                                    float* __restrict__ h2) {
  __shared__ float Ws[256 * 16];
  for (int i = threadIdx.x; i < 256 * 16; i += 256) Ws[i] = W2[i];
  __syncthreads();
  const int r = threadIdx.x >> 4, c = threadIdx.x & 15;
  const int row = blockIdx.x * 16 + r;
  const float* arow = out1 + (size_t)row * 256;
  float acc = 0.f;
#pragma unroll 8
  for (int k = 0; k < 256; ++k) acc = fmaf(arow[k], Ws[k * 16 + c], acc);
  h2[(size_t)row * 16 + c] = acc;
}

// ---------- f2: per-row dots of h2 with a2_src / a2_dst ----------
__global__ void f2_kernel(const float* __restrict__ h2, const float* __restrict__ a_src,
                          const float* __restrict__ a_dst, float* __restrict__ fs,
                          float* __restrict__ fd) {
  const int row = blockIdx.x * blockDim.x + threadIdx.x;
  if (row >= NN) return;
  float s = 0.f, d = 0.f;
#pragma unroll
  for (int k = 0; k < 16; ++k) {
    const float h = h2[(size_t)row * 16 + k];
    s = fmaf(h, a_src[k], s);
    d = fmaf(h, a_dst[k], d);
  }
  fs[row] = s;
  fd[row] = d;
}

// ---------- layer-2 attention + final log_softmax over 16 classes ----------
__global__ __launch_bounds__(256) void attn2_kernel(const unsigned* __restrict__ bitmap,
                                                    const int* __restrict__ degarr,
                                                    const float* __restrict__ h2,
                                                    const float* __restrict__ fs,
                                                    const float* __restrict__ fd,
                                                    float* __restrict__ out) {
  __shared__ float wsh[4][MAXD];
  __shared__ int jsh[4][MAXD];
  const int lane = threadIdx.x & 63;
  const int wv = threadIdx.x >> 6;
  const int row = blockIdx.x * 4 + wv;
  const unsigned short* nb = (const unsigned short*)(bitmap + (size_t)row * 256);
  const int deg = degarr[row];
  const float fsr = fs[row];
  // ---- weight phase (same as attn1) ----
  const int j0 = (lane < deg) ? (int)nb[lane] : 0;
  const int j1 = (lane + 64 < deg) ? (int)nb[lane + 64] : 0;
  const float e0 = (lane < deg) ? lrelu02(fsr + fd[j0]) : -1e30f;
  const float e1 = (lane + 64 < deg) ? lrelu02(fsr + fd[j1]) : -1e30f;
  float m = fmaxf(e0, e1);
#pragma unroll
  for (int off = 32; off; off >>= 1) m = fmaxf(m, __shfl_xor(m, off));
  const float w0 = (lane < deg) ? expf(e0 - m) : 0.f;
  const float w1 = (lane + 64 < deg) ? expf(e1 - m) : 0.f;
  float s = w0 + w1;
#pragma unroll
  for (int off = 32; off; off >>= 1) s += __shfl_xor(s, off);
  wsh[wv][lane] = w0;
  jsh[wv][lane] = j0;
  wsh[wv][lane + 64] = w1;
  jsh[wv][lane + 64] = j1;
  // ---- gather: 4 neighbors at a time (lane = group*16 + class), unroll x2 ----
  const int c = lane & 15, g = lane >> 4;
  float acc = 0.f;
  int t = g;
  for (; t + 4 < deg; t += 8) {
    const float W0 = wsh[wv][t], W1 = wsh[wv][t + 4];
    const float v0 = h2[(size_t)jsh[wv][t] * 16 + c];
    const float v1 = h2[(size_t)jsh[wv][t + 4] * 16 + c];
    acc = fmaf(W0, v0, fmaf(W1, v1, acc));
  }
  if (t < deg) acc = fmaf(wsh[wv][t], h2[(size_t)jsh[wv][t] * 16 + c], acc);
  acc += __shfl_xor(acc, 16);
  acc += __shfl_xor(acc, 32);
  const float v = acc / s;  // logits (all lanes hold their class-c value)
  // log_softmax across the 16 classes
  float mx = v;
#pragma unroll
  for (int off = 8; off; off >>= 1) mx = fmaxf(mx, __shfl_xor(mx, off, 16));
  float se = expf(v - mx);
#pragma unroll
  for (int off = 8; off; off >>= 1) se += __shfl_xor(se, off, 16);
  if (lane < 16) out[(size_t)row * 16 + lane] = v - mx - logf(se);
}

extern "C" void kernel_launch(void* const* d_in, const int* in_sizes, int n_in,
                              void* d_out, int out_size, void* d_ws, size_t ws_size,
                              hipStream_t stream) {
  const float* x = (const float*)d_in[0];
  const int* ei = (const int*)d_in[1];
  const float* W1 = (const float*)d_in[2];
  const float* a1s = (const float*)d_in[3];
  const float* a1d = (const float*)d_in[4];
  const float* W2 = (const float*)d_in[5];
  const float* a2s = (const float*)d_in[6];
  const float* a2d = (const float*)d_in[7];
  float* out = (float*)d_out;
  const int E = in_sizes[1] / 2;

  char* ws = (char*)d_ws;
  float* h1 = (float*)ws;                              // 8 MB
  float* out1 = (float*)(ws + (8u << 20));             // 8 MB
  unsigned* bitmap = (unsigned*)(ws + (16u << 20));    // 8 MB, reused as CSR
  float* f1s = (float*)(ws + (24u << 20));
  float* f1d = f1s + NN;
  float* h2 = f1d + NN;                                // 512 KB
  float* f2s = h2 + (size_t)NN * 16;
  float* f2d = f2s + NN;
  int* deg = (int*)(f2d + NN);

  hipMemsetAsync(bitmap, 0, (size_t)NN * 256 * sizeof(unsigned), stream);
  scatter_kernel<<<(E + 255) / 256, 256, 0, stream>>>(ei, E, bitmap);
  build_csr_kernel<<<NN / 4, 256, 0, stream>>>(bitmap, deg);
  gemm1_kernel<<<dim3(NN / 64, 256 / 64), 256, 0, stream>>>(x, W1, h1);
  f1_kernel<<<NN / 4, 256, 0, stream>>>(h1, a1s, a1d, f1s, f1d);
  attn1_kernel<<<NN / 4, 256, 0, stream>>>(bitmap, deg, h1, f1s, f1d, out1);
  gemm2_kernel<<<NN / 16, 256, 0, stream>>>(out1, W2, h2);
  f2_kernel<<<NN / 256, 256, 0, stream>>>(h2, a2s, a2d, f2s, f2d);
  attn2_kernel<<<NN / 4, 256, 0, stream>>>(bitmap, deg, h2, f2s, f2d, out);
}